// Round 3
// baseline (415.100 us; speedup 1.0000x reference)
//
#include <hip/hip_runtime.h>

// Elementwise clamp to [-0.5, 0.5]: pure streaming, memory-bound.
// Grid-stride over 16B vectors, non-temporal loads/stores since there is
// zero reuse (512 MiB traffic >> 256 MiB L3).
// Native clang vector type: __builtin_nontemporal_* requires a real vector
// type, not HIP's struct-based float4.
typedef float vfloat4 __attribute__((ext_vector_type(4)));

__global__ __launch_bounds__(256) void clip_kernel_f4(const vfloat4* __restrict__ x,
                                                      vfloat4* __restrict__ out,
                                                      int n4) {
    int stride = gridDim.x * blockDim.x;
    for (int i = blockIdx.x * blockDim.x + threadIdx.x; i < n4; i += stride) {
        vfloat4 v = __builtin_nontemporal_load(&x[i]);
        v.x = fminf(fmaxf(v.x, -0.5f), 0.5f);
        v.y = fminf(fmaxf(v.y, -0.5f), 0.5f);
        v.z = fminf(fmaxf(v.z, -0.5f), 0.5f);
        v.w = fminf(fmaxf(v.w, -0.5f), 0.5f);
        __builtin_nontemporal_store(v, &out[i]);
    }
}

// Tail (n not divisible by 4) — defensive; N = 16*2*2097152 is divisible by 4.
__global__ void clip_kernel_tail(const float* __restrict__ x,
                                 float* __restrict__ out,
                                 int start, int n) {
    int i = start + blockIdx.x * blockDim.x + threadIdx.x;
    if (i < n) {
        out[i] = fminf(fmaxf(x[i], -0.5f), 0.5f);
    }
}

extern "C" void kernel_launch(void* const* d_in, const int* in_sizes, int n_in,
                              void* d_out, int out_size, void* d_ws, size_t ws_size,
                              hipStream_t stream) {
    const float* x = (const float*)d_in[0];
    float* out = (float*)d_out;
    int n = in_sizes[0];

    int n4 = n / 4;
    if (n4 > 0) {
        const int threads = 256;
        // ~8 float4 per thread: enough blocks to saturate 256 CUs with
        // plenty of waves, few enough to amortize per-block setup.
        int blocks = (n4 + threads * 8 - 1) / (threads * 8);
        if (blocks < 1024) blocks = (n4 + threads - 1) / threads;  // small-n fallback
        clip_kernel_f4<<<blocks, threads, 0, stream>>>((const vfloat4*)x, (vfloat4*)out, n4);
    }
    int rem = n - n4 * 4;
    if (rem > 0) {
        clip_kernel_tail<<<1, 64, 0, stream>>>(x, out, n4 * 4, n);
    }
}